// Round 1
// baseline (323.499 us; speedup 1.0000x reference)
//
#include <hip/hip_runtime.h>
#include <hip/hip_fp16.h>

#define N_NODES 100000
#define N_EDGES 3200000
#define IN_DIM 64
#define HID_DIM 128

#define RNODES 128                       // dst-range width: range = d >> 7
#define NRANGE 782                       // ceil(N_NODES / 128)
#define PCHUNK 256                       // partition chunks (K1 blocks) — was 128
#define PCHSZ (N_EDGES / PCHUNK)         // 12500 edges per chunk
#define TCAP 48                          // tile cap: Po(16); mean+8sigma, 192B-aligned tiles
#define NLCAP 4608                       // per-range edge cap: Po(4090), +8 sigma

// ---------------------------------------------------------------------------
// K0: zero the degree array (K1 accumulates into it with global atomics).
__global__ __launch_bounds__(256) void zero_kernel(int* __restrict__ degn) {
    const int i = blockIdx.x * 256 + threadIdx.x;
    if (i < NRANGE * RNODES) degn[i] = 0;
}

// K1: partition edges into (range, chunk) tiles. packed = src | (dloc << 17).
// LDS int cursors for tile slots (zero global RMW on the hot cursor path);
// degree counting fused here as fire-and-forget global int atomicAdd
// (no return value -> no wait; 400 KB array lives in L2/LLC).
// 1024 threads x 256 blocks = 1 block/CU, 16 waves/CU (was 128 blocks: half
// the CUs idle, 2 waves/SIMD -> latency-bound at 1.4% VALUBusy).
__global__ __launch_bounds__(1024) void part_kernel(const int* __restrict__ src,
                                                    const int* __restrict__ dst,
                                                    int* __restrict__ tmp,
                                                    int* __restrict__ tcnt,
                                                    int* __restrict__ degn) {
    __shared__ int cur[NRANGE];
    const int c = blockIdx.x, tid = threadIdx.x;
    for (int i = tid; i < NRANGE; i += 1024) cur[i] = 0;
    __syncthreads();
    const int e0 = c * PCHSZ;
    for (int i = tid; i < PCHSZ; i += 1024) {
        const int d = dst[e0 + i];
        const int s = src[e0 + i];
        atomicAdd(&degn[d], 1);              // fire-and-forget, cache-resident
        const int r = d >> 7;
        const int pos = atomicAdd(&cur[r], 1);
        if (pos < TCAP)
            tmp[(size_t)(r * PCHUNK + c) * TCAP + pos] = s | ((d & 127) << 17);
    }
    __syncthreads();
    for (int i = tid; i < NRANGE; i += 1024)
        tcnt[i * PCHUNK + c] = min(cur[i], TCAP);
}

// K2: pure streaming scale: dinv = rsqrt(deg+1); y = fp16(x * dinv[node]).
// No tmp re-read, no LDS atomics (degree now counted in K1).
// Reads 26 MB, writes 13.2 MB -> HBM-bound, ~10 us.
__global__ __launch_bounds__(256) void scale_kernel(const int* __restrict__ degn,
                                                    const float* __restrict__ x,
                                                    float* __restrict__ dinv,
                                                    __half* __restrict__ y) {
    const int i = blockIdx.x * 256 + threadIdx.x;   // over N_NODES*16 float4s
    if (i >= N_NODES * 16) return;
    const int node = i >> 4, q = i & 15;
    const float dv = rsqrtf((float)degn[node] + 1.0f);
    if (q == 0) dinv[node] = dv;
    const float4 v = ((const float4*)x)[i];
    __half2 h0 = __floats2half2_rn(v.x * dv, v.y * dv);
    __half2 h1 = __floats2half2_rn(v.z * dv, v.w * dv);
    uint2 pk;
    pk.x = *(unsigned int*)&h0;
    pk.y = *(unsigned int*)&h1;
    ((uint2*)y)[i] = pk;
}

// K3: per-range fused CSR-in-LDS build + register-accumulated gather.
// Block r: scan degn -> offsets; scatter its tiles into a node-ordered LDS
// list (int LDS atomics); then 8-lane groups pull y[src] rows (16 B/lane) and
// accumulate in REGISTERS (LDS f32 atomics are per-lane-serialized — R9).
__global__ __launch_bounds__(512) void aggb_kernel(const int* __restrict__ tmp,
                                                   const int* __restrict__ tcnt,
                                                   const int* __restrict__ degn,
                                                   const __half* __restrict__ y,
                                                   __half* __restrict__ agg) {
    __shared__ int nodelist[NLCAP];      // 18 KB
    __shared__ int sc[RNODES];           // inclusive prefix (kept: end offsets)
    __shared__ int start[RNODES];
    __shared__ int cur[RNODES];
    const int r = blockIdx.x, tid = threadIdx.x;

    int mydeg = 0;
    if (tid < RNODES) {
        mydeg = degn[r * RNODES + tid];
        sc[tid] = mydeg;
    }
    __syncthreads();
    #pragma unroll
    for (int off = 1; off < RNODES; off <<= 1) {   // Hillis-Steele inclusive
        int v = 0;
        if (tid < RNODES && tid >= off) v = sc[tid - off];
        __syncthreads();
        if (tid < RNODES) sc[tid] += v;
        __syncthreads();
    }
    if (tid < RNODES) {
        start[tid] = sc[tid] - mydeg;
        cur[tid]   = sc[tid] - mydeg;
    }
    __syncthreads();

    {   // scatter: 2 threads per tile (256 tiles, mean ~16 entries each)
        const int c = tid & 255, ph = tid >> 8;
        const int tile = r * PCHUNK + c;
        const int n = tcnt[tile];
        const int* t = tmp + (size_t)tile * TCAP;
        for (int i = ph; i < n; i += 2) {
            const int pk = t[i];
            const int slot = atomicAdd(&cur[pk >> 17], 1);
            if (slot < NLCAP) nodelist[slot] = pk & 0x1FFFF;
        }
    }
    __syncthreads();

    // gather: 64 groups x 8 lanes; group g handles nodes g, g+64
    const int g = tid >> 3, lane = tid & 7;
    const uint4* y16 = (const uint4*)y;
    for (int nl = g; nl < RNODES; nl += 64) {
        const int node = r * RNODES + nl;
        if (node >= N_NODES) continue;
        float accf[8];
        {
            const uint4 pk = y16[(size_t)node * 8 + lane];   // self-loop
            const __half2* h = (const __half2*)&pk;
            #pragma unroll
            for (int q = 0; q < 4; ++q) {
                const float2 f = __half22float2(h[q]);
                accf[2*q] = f.x; accf[2*q+1] = f.y;
            }
        }
        const int beg = start[nl], end = sc[nl];
        int j = beg;
        for (; j + 4 <= end; j += 4) {
            const int s0 = nodelist[j];
            const int s1 = nodelist[j + 1];
            const int s2 = nodelist[j + 2];
            const int s3 = nodelist[j + 3];
            const uint4 p0 = y16[(size_t)s0 * 8 + lane];
            const uint4 p1 = y16[(size_t)s1 * 8 + lane];
            const uint4 p2 = y16[(size_t)s2 * 8 + lane];
            const uint4 p3 = y16[(size_t)s3 * 8 + lane];
            const __half2* h0 = (const __half2*)&p0;
            const __half2* h1 = (const __half2*)&p1;
            const __half2* h2 = (const __half2*)&p2;
            const __half2* h3 = (const __half2*)&p3;
            #pragma unroll
            for (int q = 0; q < 4; ++q) {
                float2 f0 = __half22float2(h0[q]);
                float2 f1 = __half22float2(h1[q]);
                float2 f2 = __half22float2(h2[q]);
                float2 f3 = __half22float2(h3[q]);
                accf[2*q]   += (f0.x + f1.x) + (f2.x + f3.x);
                accf[2*q+1] += (f0.y + f1.y) + (f2.y + f3.y);
            }
        }
        for (; j < end; ++j) {
            const int s = nodelist[j];
            const uint4 pk = y16[(size_t)s * 8 + lane];
            const __half2* h = (const __half2*)&pk;
            #pragma unroll
            for (int q = 0; q < 4; ++q) {
                const float2 f = __half22float2(h[q]);
                accf[2*q] += f.x; accf[2*q+1] += f.y;
            }
        }
        uint4 o;
        __half2* oh = (__half2*)&o;
        #pragma unroll
        for (int q = 0; q < 4; ++q)
            oh[q] = __floats2half2_rn(accf[2*q], accf[2*q+1]);
        ((uint4*)agg)[(size_t)node * 8 + lane] = o;
    }
}

// K4: out[n] = relu( dinv[n]*agg[n] @ W_gcn + b_gcn ) @ W_lin + b_lin.
// 32 nodes/block, 4 nodes/thread: each 16 B W-read feeds 16 FMAs.
#define H_NPB 32
__global__ __launch_bounds__(256) void head_kernel(const __half* __restrict__ agg,
                                                   const float* __restrict__ dinv,
                                                   const float* __restrict__ W,
                                                   const float* __restrict__ b_gcn,
                                                   const float* __restrict__ W_lin,
                                                   const float* __restrict__ b_lin,
                                                   float* __restrict__ out) {
    __shared__ float4 Ws[IN_DIM * HID_DIM / 4];   // 32 KB
    __shared__ float  as[H_NPB * IN_DIM];         // 8 KB
    const int tid = threadIdx.x;

    const float4* W4 = (const float4*)W;
    #pragma unroll
    for (int i = tid; i < IN_DIM * HID_DIM / 4; i += 256) Ws[i] = W4[i];

    const int node0 = blockIdx.x * H_NPB;
    {
        const uint4 a4 = ((const uint4*)(agg + (size_t)node0 * IN_DIM))[tid];
        const __half2* h = (const __half2*)&a4;
        #pragma unroll
        for (int q = 0; q < 4; ++q) {
            const float2 f = __half22float2(h[q]);
            as[tid * 8 + 2*q]     = f.x;
            as[tid * 8 + 2*q + 1] = f.y;
        }
    }
    __syncthreads();

    const int jq = tid & 31;
    const int ng = tid >> 5;
    const float* arow = as + ng * 4 * IN_DIM;

    float4 a0 = {0,0,0,0}, a1 = {0,0,0,0}, a2 = {0,0,0,0}, a3 = {0,0,0,0};
    for (int k = 0; k < IN_DIM; ++k) {
        const float4 wv = Ws[k * 32 + jq];
        const float v0 = arow[k];
        const float v1 = arow[IN_DIM + k];
        const float v2 = arow[2 * IN_DIM + k];
        const float v3 = arow[3 * IN_DIM + k];
        a0.x += v0*wv.x; a0.y += v0*wv.y; a0.z += v0*wv.z; a0.w += v0*wv.w;
        a1.x += v1*wv.x; a1.y += v1*wv.y; a1.z += v1*wv.z; a1.w += v1*wv.w;
        a2.x += v2*wv.x; a2.y += v2*wv.y; a2.z += v2*wv.z; a2.w += v2*wv.w;
        a3.x += v3*wv.x; a3.y += v3*wv.y; a3.z += v3*wv.z; a3.w += v3*wv.w;
    }

    const float4 bg = ((const float4*)b_gcn)[jq];
    const int c0 = jq * 4;
    const float w00 = W_lin[(c0+0)*2], w01 = W_lin[(c0+0)*2+1];
    const float w10 = W_lin[(c0+1)*2], w11 = W_lin[(c0+1)*2+1];
    const float w20 = W_lin[(c0+2)*2], w21 = W_lin[(c0+2)*2+1];
    const float w30 = W_lin[(c0+3)*2], w31 = W_lin[(c0+3)*2+1];
    const float bl0 = b_lin[0], bl1 = b_lin[1];

    float4 am[4] = {a0, a1, a2, a3};
    #pragma unroll
    for (int m = 0; m < 4; ++m) {
        const int node = node0 + ng * 4 + m;
        const float dv = dinv[node];
        float4 v;
        v.x = fmaxf(am[m].x * dv + bg.x, 0.f);
        v.y = fmaxf(am[m].y * dv + bg.y, 0.f);
        v.z = fmaxf(am[m].z * dv + bg.z, 0.f);
        v.w = fmaxf(am[m].w * dv + bg.w, 0.f);
        float o0 = v.x*w00 + v.y*w10 + v.z*w20 + v.w*w30;
        float o1 = v.x*w01 + v.y*w11 + v.z*w21 + v.w*w31;
        #pragma unroll
        for (int off = 16; off > 0; off >>= 1) {
            o0 += __shfl_down(o0, off, 32);
            o1 += __shfl_down(o1, off, 32);
        }
        if (jq == 0) {
            out[(size_t)node * 2 + 0] = o0 + bl0;
            out[(size_t)node * 2 + 1] = o1 + bl1;
        }
    }
}

extern "C" void kernel_launch(void* const* d_in, const int* in_sizes, int n_in,
                              void* d_out, int out_size, void* d_ws, size_t ws_size,
                              hipStream_t stream) {
    const float* x     = (const float*)d_in[0];
    const int*   ei    = (const int*)  d_in[1];   // [2, E]: row 0 = src, row 1 = dst
    const float* W_gcn = (const float*)d_in[2];
    const float* b_gcn = (const float*)d_in[3];
    const float* W_lin = (const float*)d_in[4];
    const float* b_lin = (const float*)d_in[5];
    float* out = (float*)d_out;

    // workspace: tmp[200192*48 = 38.4 MB] | tcnt[200192] | degn[100096] |
    //            dinv[100000 f] | y[12.8 MB] | agg[12.8 MB]  ~= 65.7 MB total.
    // No aliasing; degn zeroed by K0, everything else fully written before read.
    int*    tmp  = (int*)d_ws;
    int*    tcnt = tmp + (size_t)NRANGE * PCHUNK * TCAP;
    int*    degn = tcnt + NRANGE * PCHUNK;
    float*  dinv = (float*)(degn + NRANGE * RNODES);
    __half* y    = (__half*)(dinv + N_NODES);
    __half* agg  = y + (size_t)N_NODES * IN_DIM;

    const int* src = ei;
    const int* dst = ei + N_EDGES;

    zero_kernel<<<(NRANGE * RNODES + 255) / 256, 256, 0, stream>>>(degn);
    part_kernel<<<PCHUNK, 1024, 0, stream>>>(src, dst, tmp, tcnt, degn);
    scale_kernel<<<(N_NODES * 16) / 256, 256, 0, stream>>>(degn, x, dinv, y);
    aggb_kernel<<<NRANGE, 512, 0, stream>>>(tmp, tcnt, degn, y, agg);
    head_kernel<<<N_NODES / H_NPB, 256, 0, stream>>>(agg, dinv, W_gcn, b_gcn, W_lin, b_lin, out);
}

// Round 5
// 231.446 us; speedup vs baseline: 1.3977x; 1.3977x over previous
//
#include <hip/hip_runtime.h>
#include <hip/hip_fp16.h>

#define N_NODES 100000
#define N_EDGES 3200000
#define IN_DIM 64
#define HID_DIM 128

#define RNODES 128                       // dst-range width: range = d >> 7
#define NRANGE 782                       // ceil(N_NODES / 128)
#define PCHUNK 256                       // partition chunks (K1 blocks)
#define PCHSZ (N_EDGES / PCHUNK)         // 12500 edges per chunk
#define TCAP 48                          // tile cap: Po(16); mean+8sigma, 192B tiles
#define NLCAP 4608                       // per-range edge cap: Po(4090), +8 sigma

// ---------------------------------------------------------------------------
// K1: partition edges into (range, chunk) tiles. packed = src | (dloc << 17).
// LDS int cursors only — ZERO global atomics. (R1 lesson: device-scope
// atomicAdd to a shared array is serviced at the memory-side coherence point
// across the 8 non-coherent XCD L2s -> +148 MB HBM writes, 2x slowdown.)
// 256 blocks x 1024 threads = 1 block/CU, 4 waves/SIMD (occupancy fix kept:
// R1 confirmed OccupancyPercent 8->39, hbm 485->1280 GB/s).
__global__ __launch_bounds__(1024) void part_kernel(const int* __restrict__ src,
                                                    const int* __restrict__ dst,
                                                    int* __restrict__ tmp,
                                                    int* __restrict__ tcnt) {
    __shared__ int cur[NRANGE];
    const int c = blockIdx.x, tid = threadIdx.x;
    for (int i = tid; i < NRANGE; i += 1024) cur[i] = 0;
    __syncthreads();
    const int e0 = c * PCHSZ;
    for (int i = tid; i < PCHSZ; i += 1024) {
        const int d = dst[e0 + i];
        const int s = src[e0 + i];
        const int r = d >> 7;
        const int pos = atomicAdd(&cur[r], 1);
        if (pos < TCAP)
            tmp[(size_t)(r * PCHUNK + c) * TCAP + pos] = s | ((d & 127) << 17);
    }
    __syncthreads();
    for (int i = tid; i < NRANGE; i += 1024)
        tcnt[i * PCHUNK + c] = min(cur[i], TCAP);
}

// K2: per-range degree count from tiles (LDS *int* atomics, 1/edge — cheap,
// block-local so no cross-XCD coherence traffic) -> degn, dinv; fused with
// y = fp16(x * dinv) for this range's nodes. Tile data is L2/LLC-warm.
__global__ __launch_bounds__(512) void degscale_kernel(const int* __restrict__ tmp,
                                                       const int* __restrict__ tcnt,
                                                       const float* __restrict__ x,
                                                       int* __restrict__ degn,
                                                       float* __restrict__ dinv,
                                                       __half* __restrict__ y) {
    __shared__ int   cnt[RNODES];
    __shared__ float dvs[RNODES];
    const int r = blockIdx.x, tid = threadIdx.x;
    if (tid < RNODES) cnt[tid] = 0;
    __syncthreads();
    {   // 2 threads per tile (256 tiles, mean ~16 entries each)
        const int c = tid & 255, half = tid >> 8;
        const int tile = r * PCHUNK + c;
        const int n = tcnt[tile];
        const int* t = tmp + (size_t)tile * TCAP;
        for (int i = half; i < n; i += 2) atomicAdd(&cnt[t[i] >> 17], 1);
    }
    __syncthreads();
    if (tid < RNODES) {
        const int node = r * RNODES + tid;
        const int dg = cnt[tid];
        degn[node] = dg;
        const float dv = rsqrtf((float)dg + 1.0f);   // +1 = self-loop
        dvs[tid] = dv;
        if (node < N_NODES) dinv[node] = dv;
    }
    __syncthreads();
    for (int i = tid; i < RNODES * 16; i += 512) {
        const int nl = i >> 4, q = i & 15;
        const int node = r * RNODES + nl;
        if (node < N_NODES) {
            const float4 v = ((const float4*)x)[(size_t)node * 16 + q];
            const float dv = dvs[nl];
            __half2 h0 = __floats2half2_rn(v.x * dv, v.y * dv);
            __half2 h1 = __floats2half2_rn(v.z * dv, v.w * dv);
            uint2 pk;
            pk.x = *(unsigned int*)&h0;
            pk.y = *(unsigned int*)&h1;
            ((uint2*)y)[(size_t)node * 16 + q] = pk;
        }
    }
}

// K3: per-range fused CSR-in-LDS build + register-accumulated gather.
// Block r: scan degn -> offsets; scatter its tiles into a node-ordered LDS
// list (int LDS atomics); then 8-lane groups pull y[src] rows (16 B/lane) and
// accumulate in REGISTERS (LDS f32 atomics are per-lane-serialized — R9).
__global__ __launch_bounds__(512) void aggb_kernel(const int* __restrict__ tmp,
                                                   const int* __restrict__ tcnt,
                                                   const int* __restrict__ degn,
                                                   const __half* __restrict__ y,
                                                   __half* __restrict__ agg) {
    __shared__ int nodelist[NLCAP];      // 18 KB
    __shared__ int sc[RNODES];           // inclusive prefix (kept: end offsets)
    __shared__ int start[RNODES];
    __shared__ int cur[RNODES];
    const int r = blockIdx.x, tid = threadIdx.x;

    int mydeg = 0;
    if (tid < RNODES) {
        mydeg = degn[r * RNODES + tid];
        sc[tid] = mydeg;
    }
    __syncthreads();
    #pragma unroll
    for (int off = 1; off < RNODES; off <<= 1) {   // Hillis-Steele inclusive
        int v = 0;
        if (tid < RNODES && tid >= off) v = sc[tid - off];
        __syncthreads();
        if (tid < RNODES) sc[tid] += v;
        __syncthreads();
    }
    if (tid < RNODES) {
        start[tid] = sc[tid] - mydeg;
        cur[tid]   = sc[tid] - mydeg;
    }
    __syncthreads();

    {   // scatter: 2 threads per tile (256 tiles, mean ~16 entries each)
        const int c = tid & 255, ph = tid >> 8;
        const int tile = r * PCHUNK + c;
        const int n = tcnt[tile];
        const int* t = tmp + (size_t)tile * TCAP;
        for (int i = ph; i < n; i += 2) {
            const int pk = t[i];
            const int slot = atomicAdd(&cur[pk >> 17], 1);
            if (slot < NLCAP) nodelist[slot] = pk & 0x1FFFF;
        }
    }
    __syncthreads();

    // gather: 64 groups x 8 lanes; group g handles nodes g, g+64
    const int g = tid >> 3, lane = tid & 7;
    const uint4* y16 = (const uint4*)y;
    for (int nl = g; nl < RNODES; nl += 64) {
        const int node = r * RNODES + nl;
        if (node >= N_NODES) continue;
        float accf[8];
        {
            const uint4 pk = y16[(size_t)node * 8 + lane];   // self-loop
            const __half2* h = (const __half2*)&pk;
            #pragma unroll
            for (int q = 0; q < 4; ++q) {
                const float2 f = __half22float2(h[q]);
                accf[2*q] = f.x; accf[2*q+1] = f.y;
            }
        }
        const int beg = start[nl], end = sc[nl];
        int j = beg;
        for (; j + 4 <= end; j += 4) {
            const int s0 = nodelist[j];
            const int s1 = nodelist[j + 1];
            const int s2 = nodelist[j + 2];
            const int s3 = nodelist[j + 3];
            const uint4 p0 = y16[(size_t)s0 * 8 + lane];
            const uint4 p1 = y16[(size_t)s1 * 8 + lane];
            const uint4 p2 = y16[(size_t)s2 * 8 + lane];
            const uint4 p3 = y16[(size_t)s3 * 8 + lane];
            const __half2* h0 = (const __half2*)&p0;
            const __half2* h1 = (const __half2*)&p1;
            const __half2* h2 = (const __half2*)&p2;
            const __half2* h3 = (const __half2*)&p3;
            #pragma unroll
            for (int q = 0; q < 4; ++q) {
                float2 f0 = __half22float2(h0[q]);
                float2 f1 = __half22float2(h1[q]);
                float2 f2 = __half22float2(h2[q]);
                float2 f3 = __half22float2(h3[q]);
                accf[2*q]   += (f0.x + f1.x) + (f2.x + f3.x);
                accf[2*q+1] += (f0.y + f1.y) + (f2.y + f3.y);
            }
        }
        for (; j < end; ++j) {
            const int s = nodelist[j];
            const uint4 pk = y16[(size_t)s * 8 + lane];
            const __half2* h = (const __half2*)&pk;
            #pragma unroll
            for (int q = 0; q < 4; ++q) {
                const float2 f = __half22float2(h[q]);
                accf[2*q] += f.x; accf[2*q+1] += f.y;
            }
        }
        uint4 o;
        __half2* oh = (__half2*)&o;
        #pragma unroll
        for (int q = 0; q < 4; ++q)
            oh[q] = __floats2half2_rn(accf[2*q], accf[2*q+1]);
        ((uint4*)agg)[(size_t)node * 8 + lane] = o;
    }
}

// K4: out[n] = relu( dinv[n]*agg[n] @ W_gcn + b_gcn ) @ W_lin + b_lin.
// 32 nodes/block, 4 nodes/thread: each 16 B W-read feeds 16 FMAs.
#define H_NPB 32
__global__ __launch_bounds__(256) void head_kernel(const __half* __restrict__ agg,
                                                   const float* __restrict__ dinv,
                                                   const float* __restrict__ W,
                                                   const float* __restrict__ b_gcn,
                                                   const float* __restrict__ W_lin,
                                                   const float* __restrict__ b_lin,
                                                   float* __restrict__ out) {
    __shared__ float4 Ws[IN_DIM * HID_DIM / 4];   // 32 KB
    __shared__ float  as[H_NPB * IN_DIM];         // 8 KB
    const int tid = threadIdx.x;

    const float4* W4 = (const float4*)W;
    #pragma unroll
    for (int i = tid; i < IN_DIM * HID_DIM / 4; i += 256) Ws[i] = W4[i];

    const int node0 = blockIdx.x * H_NPB;
    {
        const uint4 a4 = ((const uint4*)(agg + (size_t)node0 * IN_DIM))[tid];
        const __half2* h = (const __half2*)&a4;
        #pragma unroll
        for (int q = 0; q < 4; ++q) {
            const float2 f = __half22float2(h[q]);
            as[tid * 8 + 2*q]     = f.x;
            as[tid * 8 + 2*q + 1] = f.y;
        }
    }
    __syncthreads();

    const int jq = tid & 31;
    const int ng = tid >> 5;
    const float* arow = as + ng * 4 * IN_DIM;

    float4 a0 = {0,0,0,0}, a1 = {0,0,0,0}, a2 = {0,0,0,0}, a3 = {0,0,0,0};
    for (int k = 0; k < IN_DIM; ++k) {
        const float4 wv = Ws[k * 32 + jq];
        const float v0 = arow[k];
        const float v1 = arow[IN_DIM + k];
        const float v2 = arow[2 * IN_DIM + k];
        const float v3 = arow[3 * IN_DIM + k];
        a0.x += v0*wv.x; a0.y += v0*wv.y; a0.z += v0*wv.z; a0.w += v0*wv.w;
        a1.x += v1*wv.x; a1.y += v1*wv.y; a1.z += v1*wv.z; a1.w += v1*wv.w;
        a2.x += v2*wv.x; a2.y += v2*wv.y; a2.z += v2*wv.z; a2.w += v2*wv.w;
        a3.x += v3*wv.x; a3.y += v3*wv.y; a3.z += v3*wv.z; a3.w += v3*wv.w;
    }

    const float4 bg = ((const float4*)b_gcn)[jq];
    const int c0 = jq * 4;
    const float w00 = W_lin[(c0+0)*2], w01 = W_lin[(c0+0)*2+1];
    const float w10 = W_lin[(c0+1)*2], w11 = W_lin[(c0+1)*2+1];
    const float w20 = W_lin[(c0+2)*2], w21 = W_lin[(c0+2)*2+1];
    const float w30 = W_lin[(c0+3)*2], w31 = W_lin[(c0+3)*2+1];
    const float bl0 = b_lin[0], bl1 = b_lin[1];

    float4 am[4] = {a0, a1, a2, a3};
    #pragma unroll
    for (int m = 0; m < 4; ++m) {
        const int node = node0 + ng * 4 + m;
        const float dv = dinv[node];
        float4 v;
        v.x = fmaxf(am[m].x * dv + bg.x, 0.f);
        v.y = fmaxf(am[m].y * dv + bg.y, 0.f);
        v.z = fmaxf(am[m].z * dv + bg.z, 0.f);
        v.w = fmaxf(am[m].w * dv + bg.w, 0.f);
        float o0 = v.x*w00 + v.y*w10 + v.z*w20 + v.w*w30;
        float o1 = v.x*w01 + v.y*w11 + v.z*w21 + v.w*w31;
        #pragma unroll
        for (int off = 16; off > 0; off >>= 1) {
            o0 += __shfl_down(o0, off, 32);
            o1 += __shfl_down(o1, off, 32);
        }
        if (jq == 0) {
            out[(size_t)node * 2 + 0] = o0 + bl0;
            out[(size_t)node * 2 + 1] = o1 + bl1;
        }
    }
}

extern "C" void kernel_launch(void* const* d_in, const int* in_sizes, int n_in,
                              void* d_out, int out_size, void* d_ws, size_t ws_size,
                              hipStream_t stream) {
    const float* x     = (const float*)d_in[0];
    const int*   ei    = (const int*)  d_in[1];   // [2, E]: row 0 = src, row 1 = dst
    const float* W_gcn = (const float*)d_in[2];
    const float* b_gcn = (const float*)d_in[3];
    const float* W_lin = (const float*)d_in[4];
    const float* b_lin = (const float*)d_in[5];
    float* out = (float*)d_out;

    // workspace: tmp[200192*48 = 38.4 MB] | tcnt[200192] | degn[100096] |
    //            dinv[100000 f] | y[12.8 MB] | agg[12.8 MB]  ~= 65 MB total.
    // No aliasing, no memset (everything fully written before read).
    int*    tmp  = (int*)d_ws;
    int*    tcnt = tmp + (size_t)NRANGE * PCHUNK * TCAP;
    int*    degn = tcnt + NRANGE * PCHUNK;
    float*  dinv = (float*)(degn + NRANGE * RNODES);
    __half* y    = (__half*)(dinv + N_NODES);
    __half* agg  = y + (size_t)N_NODES * IN_DIM;

    const int* src = ei;
    const int* dst = ei + N_EDGES;

    part_kernel<<<PCHUNK, 1024, 0, stream>>>(src, dst, tmp, tcnt);
    degscale_kernel<<<NRANGE, 512, 0, stream>>>(tmp, tcnt, x, degn, dinv, y);
    aggb_kernel<<<NRANGE, 512, 0, stream>>>(tmp, tcnt, degn, y, agg);
    head_kernel<<<N_NODES / H_NPB, 256, 0, stream>>>(agg, dinv, W_gcn, b_gcn, W_lin, b_lin, out);
}

// Round 6
// 228.968 us; speedup vs baseline: 1.4129x; 1.0108x over previous
//
#include <hip/hip_runtime.h>
#include <hip/hip_fp16.h>

#define N_NODES 100000
#define N_EDGES 3200000
#define IN_DIM 64
#define HID_DIM 128

#define RNODES 128                       // dst-range width: range = d >> 7
#define NRANGE 782                       // ceil(N_NODES / 128)
#define PCHUNK 256                       // partition chunks (K1 blocks)
#define PCHSZ (N_EDGES / PCHUNK)         // 12500 edges per chunk
#define TCAP 48                          // tile cap: Po(16); mean+8sigma, 192B tiles
#define NLCAP 4608                       // per-range edge cap: Po(4090), +8 sigma

// ---------------------------------------------------------------------------
// K1: partition edges into (range, chunk) tiles. packed = src | (dloc << 17).
// LDS int cursors only — ZERO global atomics. (R1 lesson: device-scope
// atomicAdd to a shared array is serviced at the memory-side coherence point
// across the 8 non-coherent XCD L2s -> +148 MB HBM writes, 2x slowdown.)
// 256 blocks x 1024 threads = 1 block/CU (R1 confirmed Occupancy 8->39,
// hbm 485->1280 GB/s; R5: dropped out of top-5, <68 us).
__global__ __launch_bounds__(1024) void part_kernel(const int* __restrict__ src,
                                                    const int* __restrict__ dst,
                                                    int* __restrict__ tmp,
                                                    int* __restrict__ tcnt) {
    __shared__ int cur[NRANGE];
    const int c = blockIdx.x, tid = threadIdx.x;
    for (int i = tid; i < NRANGE; i += 1024) cur[i] = 0;
    __syncthreads();
    const int e0 = c * PCHSZ;
    for (int i = tid; i < PCHSZ; i += 1024) {
        const int d = dst[e0 + i];
        const int s = src[e0 + i];
        const int r = d >> 7;
        const int pos = atomicAdd(&cur[r], 1);
        if (pos < TCAP)
            tmp[(size_t)(r * PCHUNK + c) * TCAP + pos] = s | ((d & 127) << 17);
    }
    __syncthreads();
    for (int i = tid; i < NRANGE; i += 1024)
        tcnt[i * PCHUNK + c] = min(cur[i], TCAP);
}

// K2: per-range degree count from tiles (LDS *int* atomics, block-local, no
// cross-XCD coherence traffic) -> degn, dinv; fused with y = fp16(x * dinv).
__global__ __launch_bounds__(512) void degscale_kernel(const int* __restrict__ tmp,
                                                       const int* __restrict__ tcnt,
                                                       const float* __restrict__ x,
                                                       int* __restrict__ degn,
                                                       float* __restrict__ dinv,
                                                       __half* __restrict__ y) {
    __shared__ int   cnt[RNODES];
    __shared__ float dvs[RNODES];
    const int r = blockIdx.x, tid = threadIdx.x;
    if (tid < RNODES) cnt[tid] = 0;
    __syncthreads();
    {   // 2 threads per tile (256 tiles, mean ~16 entries each)
        const int c = tid & 255, half = tid >> 8;
        const int tile = r * PCHUNK + c;
        const int n = tcnt[tile];
        const int* t = tmp + (size_t)tile * TCAP;
        for (int i = half; i < n; i += 2) atomicAdd(&cnt[t[i] >> 17], 1);
    }
    __syncthreads();
    if (tid < RNODES) {
        const int node = r * RNODES + tid;
        const int dg = cnt[tid];
        degn[node] = dg;
        const float dv = rsqrtf((float)dg + 1.0f);   // +1 = self-loop
        dvs[tid] = dv;
        if (node < N_NODES) dinv[node] = dv;
    }
    __syncthreads();
    for (int i = tid; i < RNODES * 16; i += 512) {
        const int nl = i >> 4, q = i & 15;
        const int node = r * RNODES + nl;
        if (node < N_NODES) {
            const float4 v = ((const float4*)x)[(size_t)node * 16 + q];
            const float dv = dvs[nl];
            __half2 h0 = __floats2half2_rn(v.x * dv, v.y * dv);
            __half2 h1 = __floats2half2_rn(v.z * dv, v.w * dv);
            uint2 pk;
            pk.x = *(unsigned int*)&h0;
            pk.y = *(unsigned int*)&h1;
            ((uint2*)y)[(size_t)node * 16 + q] = pk;
        }
    }
}

// K3: per-range fused CSR-in-LDS build + register-accumulated gather.
// R5 counters: Occupancy 45.8% (grid 782 x 8 waves = 3.05 blk/CU -> ~24 wave
// ceiling), VALUBusy 23%, hbm 33% -> latency-bound gather. Fix: 1024-thread
// blocks, ONE node per 8-lane group (128 groups), no nl-loop -> 16 waves/blk,
// 2 blk/CU resident = 32 waves/CU offered; half the serial depth per group.
__global__ __launch_bounds__(1024) void aggb_kernel(const int* __restrict__ tmp,
                                                    const int* __restrict__ tcnt,
                                                    const int* __restrict__ degn,
                                                    const __half* __restrict__ y,
                                                    __half* __restrict__ agg) {
    __shared__ int nodelist[NLCAP];      // 18 KB
    __shared__ int sc[RNODES];           // inclusive prefix (kept: end offsets)
    __shared__ int start[RNODES];
    __shared__ int cur[RNODES];
    const int r = blockIdx.x, tid = threadIdx.x;

    int mydeg = 0;
    if (tid < RNODES) {
        mydeg = degn[r * RNODES + tid];
        sc[tid] = mydeg;
    }
    __syncthreads();
    #pragma unroll
    for (int off = 1; off < RNODES; off <<= 1) {   // Hillis-Steele inclusive
        int v = 0;
        if (tid < RNODES && tid >= off) v = sc[tid - off];
        __syncthreads();
        if (tid < RNODES) sc[tid] += v;
        __syncthreads();
    }
    if (tid < RNODES) {
        start[tid] = sc[tid] - mydeg;
        cur[tid]   = sc[tid] - mydeg;
    }
    __syncthreads();

    {   // scatter: 4 threads per tile (256 tiles, mean ~16 entries each)
        const int c = tid & 255, ph = tid >> 8;
        const int tile = r * PCHUNK + c;
        const int n = tcnt[tile];
        const int* t = tmp + (size_t)tile * TCAP;
        for (int i = ph; i < n; i += 4) {
            const int pk = t[i];
            const int slot = atomicAdd(&cur[pk >> 17], 1);
            if (slot < NLCAP) nodelist[slot] = pk & 0x1FFFF;
        }
    }
    __syncthreads();

    // gather: 128 groups x 8 lanes; group g handles exactly node g
    const int g = tid >> 3, lane = tid & 7;
    const uint4* y16 = (const uint4*)y;
    const int node = r * RNODES + g;
    if (node < N_NODES) {
        float accf[8];
        {
            const uint4 pk = y16[(size_t)node * 8 + lane];   // self-loop
            const __half2* h = (const __half2*)&pk;
            #pragma unroll
            for (int q = 0; q < 4; ++q) {
                const float2 f = __half22float2(h[q]);
                accf[2*q] = f.x; accf[2*q+1] = f.y;
            }
        }
        const int beg = start[g], end = sc[g];
        int j = beg;
        for (; j + 4 <= end; j += 4) {
            const int s0 = nodelist[j];
            const int s1 = nodelist[j + 1];
            const int s2 = nodelist[j + 2];
            const int s3 = nodelist[j + 3];
            const uint4 p0 = y16[(size_t)s0 * 8 + lane];
            const uint4 p1 = y16[(size_t)s1 * 8 + lane];
            const uint4 p2 = y16[(size_t)s2 * 8 + lane];
            const uint4 p3 = y16[(size_t)s3 * 8 + lane];
            const __half2* h0 = (const __half2*)&p0;
            const __half2* h1 = (const __half2*)&p1;
            const __half2* h2 = (const __half2*)&p2;
            const __half2* h3 = (const __half2*)&p3;
            #pragma unroll
            for (int q = 0; q < 4; ++q) {
                float2 f0 = __half22float2(h0[q]);
                float2 f1 = __half22float2(h1[q]);
                float2 f2 = __half22float2(h2[q]);
                float2 f3 = __half22float2(h3[q]);
                accf[2*q]   += (f0.x + f1.x) + (f2.x + f3.x);
                accf[2*q+1] += (f0.y + f1.y) + (f2.y + f3.y);
            }
        }
        for (; j < end; ++j) {
            const int s = nodelist[j];
            const uint4 pk = y16[(size_t)s * 8 + lane];
            const __half2* h = (const __half2*)&pk;
            #pragma unroll
            for (int q = 0; q < 4; ++q) {
                const float2 f = __half22float2(h[q]);
                accf[2*q] += f.x; accf[2*q+1] += f.y;
            }
        }
        uint4 o;
        __half2* oh = (__half2*)&o;
        #pragma unroll
        for (int q = 0; q < 4; ++q)
            oh[q] = __floats2half2_rn(accf[2*q], accf[2*q+1]);
        ((uint4*)agg)[(size_t)node * 8 + lane] = o;
    }
}

// K4: out[n] = relu( dinv[n]*agg[n] @ W_gcn + b_gcn ) @ W_lin + b_lin.
// 32 nodes/block, 4 nodes/thread: each 16 B W-read feeds 16 FMAs.
#define H_NPB 32
__global__ __launch_bounds__(256) void head_kernel(const __half* __restrict__ agg,
                                                   const float* __restrict__ dinv,
                                                   const float* __restrict__ W,
                                                   const float* __restrict__ b_gcn,
                                                   const float* __restrict__ W_lin,
                                                   const float* __restrict__ b_lin,
                                                   float* __restrict__ out) {
    __shared__ float4 Ws[IN_DIM * HID_DIM / 4];   // 32 KB
    __shared__ float  as[H_NPB * IN_DIM];         // 8 KB
    const int tid = threadIdx.x;

    const float4* W4 = (const float4*)W;
    #pragma unroll
    for (int i = tid; i < IN_DIM * HID_DIM / 4; i += 256) Ws[i] = W4[i];

    const int node0 = blockIdx.x * H_NPB;
    {
        const uint4 a4 = ((const uint4*)(agg + (size_t)node0 * IN_DIM))[tid];
        const __half2* h = (const __half2*)&a4;
        #pragma unroll
        for (int q = 0; q < 4; ++q) {
            const float2 f = __half22float2(h[q]);
            as[tid * 8 + 2*q]     = f.x;
            as[tid * 8 + 2*q + 1] = f.y;
        }
    }
    __syncthreads();

    const int jq = tid & 31;
    const int ng = tid >> 5;
    const float* arow = as + ng * 4 * IN_DIM;

    float4 a0 = {0,0,0,0}, a1 = {0,0,0,0}, a2 = {0,0,0,0}, a3 = {0,0,0,0};
    for (int k = 0; k < IN_DIM; ++k) {
        const float4 wv = Ws[k * 32 + jq];
        const float v0 = arow[k];
        const float v1 = arow[IN_DIM + k];
        const float v2 = arow[2 * IN_DIM + k];
        const float v3 = arow[3 * IN_DIM + k];
        a0.x += v0*wv.x; a0.y += v0*wv.y; a0.z += v0*wv.z; a0.w += v0*wv.w;
        a1.x += v1*wv.x; a1.y += v1*wv.y; a1.z += v1*wv.z; a1.w += v1*wv.w;
        a2.x += v2*wv.x; a2.y += v2*wv.y; a2.z += v2*wv.z; a2.w += v2*wv.w;
        a3.x += v3*wv.x; a3.y += v3*wv.y; a3.z += v3*wv.z; a3.w += v3*wv.w;
    }

    const float4 bg = ((const float4*)b_gcn)[jq];
    const int c0 = jq * 4;
    const float w00 = W_lin[(c0+0)*2], w01 = W_lin[(c0+0)*2+1];
    const float w10 = W_lin[(c0+1)*2], w11 = W_lin[(c0+1)*2+1];
    const float w20 = W_lin[(c0+2)*2], w21 = W_lin[(c0+2)*2+1];
    const float w30 = W_lin[(c0+3)*2], w31 = W_lin[(c0+3)*2+1];
    const float bl0 = b_lin[0], bl1 = b_lin[1];

    float4 am[4] = {a0, a1, a2, a3};
    #pragma unroll
    for (int m = 0; m < 4; ++m) {
        const int node = node0 + ng * 4 + m;
        const float dv = dinv[node];
        float4 v;
        v.x = fmaxf(am[m].x * dv + bg.x, 0.f);
        v.y = fmaxf(am[m].y * dv + bg.y, 0.f);
        v.z = fmaxf(am[m].z * dv + bg.z, 0.f);
        v.w = fmaxf(am[m].w * dv + bg.w, 0.f);
        float o0 = v.x*w00 + v.y*w10 + v.z*w20 + v.w*w30;
        float o1 = v.x*w01 + v.y*w11 + v.z*w21 + v.w*w31;
        #pragma unroll
        for (int off = 16; off > 0; off >>= 1) {
            o0 += __shfl_down(o0, off, 32);
            o1 += __shfl_down(o1, off, 32);
        }
        if (jq == 0) {
            out[(size_t)node * 2 + 0] = o0 + bl0;
            out[(size_t)node * 2 + 1] = o1 + bl1;
        }
    }
}

extern "C" void kernel_launch(void* const* d_in, const int* in_sizes, int n_in,
                              void* d_out, int out_size, void* d_ws, size_t ws_size,
                              hipStream_t stream) {
    const float* x     = (const float*)d_in[0];
    const int*   ei    = (const int*)  d_in[1];   // [2, E]: row 0 = src, row 1 = dst
    const float* W_gcn = (const float*)d_in[2];
    const float* b_gcn = (const float*)d_in[3];
    const float* W_lin = (const float*)d_in[4];
    const float* b_lin = (const float*)d_in[5];
    float* out = (float*)d_out;

    // workspace: tmp[200192*48 = 38.4 MB] | tcnt[200192] | degn[100096] |
    //            dinv[100000 f] | y[12.8 MB] | agg[12.8 MB]  ~= 65 MB total.
    // No aliasing, no memset (everything fully written before read).
    int*    tmp  = (int*)d_ws;
    int*    tcnt = tmp + (size_t)NRANGE * PCHUNK * TCAP;
    int*    degn = tcnt + NRANGE * PCHUNK;
    float*  dinv = (float*)(degn + NRANGE * RNODES);
    __half* y    = (__half*)(dinv + N_NODES);
    __half* agg  = y + (size_t)N_NODES * IN_DIM;

    const int* src = ei;
    const int* dst = ei + N_EDGES;

    part_kernel<<<PCHUNK, 1024, 0, stream>>>(src, dst, tmp, tcnt);
    degscale_kernel<<<NRANGE, 512, 0, stream>>>(tmp, tcnt, x, degn, dinv, y);
    aggb_kernel<<<NRANGE, 1024, 0, stream>>>(tmp, tcnt, degn, y, agg);
    head_kernel<<<N_NODES / H_NPB, 256, 0, stream>>>(agg, dinv, W_gcn, b_gcn, W_lin, b_lin, out);
}

// Round 7
// 227.299 us; speedup vs baseline: 1.4232x; 1.0073x over previous
//
#include <hip/hip_runtime.h>
#include <hip/hip_fp16.h>

#define N_NODES 100000
#define N_EDGES 3200000
#define IN_DIM 64
#define HID_DIM 128

#define RNODES 128                       // dst-range width: range = d >> 7
#define NRANGE 782                       // ceil(N_NODES / 128)
#define PCHUNK 256                       // partition chunks (K1 blocks)
#define PCHSZ (N_EDGES / PCHUNK)         // 12500 edges per chunk
#define TCAP 48                          // tile cap: Po(16); mean+8sigma, 192B tiles
#define NLCAP 4608                       // per-range edge cap: Po(4090), +8 sigma

// Tile index is CHUNK-MAJOR: tile(c, r) = c*NRANGE + r.
// R6 lesson: r-major put block c's 782 tile writes at 49KB (0xC000) stride ->
// L2 set aliasing -> partial 64B lines evicted early -> WRITE_SIZE 69.6 MB
// (5x useful data) and part_kernel = 67 us at 1.6% VALUBusy. Chunk-major makes
// each block's write footprint one contiguous 150 KB window in its own XCD L2.
#define TILE(c, r) ((size_t)(c) * NRANGE + (r))

// ---------------------------------------------------------------------------
// K1: partition edges into (range, chunk) tiles. packed = src | (dloc << 17).
// LDS int cursors only — ZERO global atomics (R1: cross-XCD atomics = +148 MB
// HBM writes). 256 blocks x 1024 threads = 1 block/CU. 2-edge unroll for ILP.
__global__ __launch_bounds__(1024) void part_kernel(const int* __restrict__ src,
                                                    const int* __restrict__ dst,
                                                    int* __restrict__ tmp,
                                                    int* __restrict__ tcnt) {
    __shared__ int cur[NRANGE];
    const int c = blockIdx.x, tid = threadIdx.x;
    for (int i = tid; i < NRANGE; i += 1024) cur[i] = 0;
    __syncthreads();
    const int e0 = c * PCHSZ;
    int* tmpc = tmp + TILE(c, 0) * TCAP;             // block-local 150 KB window
    int i = tid;
    for (; i + 1024 < PCHSZ; i += 2048) {
        const int d0 = dst[e0 + i];
        const int s0 = src[e0 + i];
        const int d1 = dst[e0 + i + 1024];
        const int s1 = src[e0 + i + 1024];
        const int r0 = d0 >> 7;
        const int p0 = atomicAdd(&cur[r0], 1);
        if (p0 < TCAP) tmpc[(size_t)r0 * TCAP + p0] = s0 | ((d0 & 127) << 17);
        const int r1 = d1 >> 7;
        const int p1 = atomicAdd(&cur[r1], 1);
        if (p1 < TCAP) tmpc[(size_t)r1 * TCAP + p1] = s1 | ((d1 & 127) << 17);
    }
    if (i < PCHSZ) {
        const int d = dst[e0 + i];
        const int s = src[e0 + i];
        const int r = d >> 7;
        const int pos = atomicAdd(&cur[r], 1);
        if (pos < TCAP) tmpc[(size_t)r * TCAP + pos] = s | ((d & 127) << 17);
    }
    __syncthreads();
    for (int j = tid; j < NRANGE; j += 1024)         // contiguous tcnt writes
        tcnt[c * NRANGE + j] = min(cur[j], TCAP);
}

// K2: per-range degree count from tiles (LDS *int* atomics, block-local, no
// cross-XCD coherence traffic) -> degn, dinv; fused with y = fp16(x * dinv).
__global__ __launch_bounds__(512) void degscale_kernel(const int* __restrict__ tmp,
                                                       const int* __restrict__ tcnt,
                                                       const float* __restrict__ x,
                                                       int* __restrict__ degn,
                                                       float* __restrict__ dinv,
                                                       __half* __restrict__ y) {
    __shared__ int   cnt[RNODES];
    __shared__ float dvs[RNODES];
    const int r = blockIdx.x, tid = threadIdx.x;
    if (tid < RNODES) cnt[tid] = 0;
    __syncthreads();
    {   // 2 threads per tile (256 tiles, mean ~16 entries each)
        const int c = tid & 255, half = tid >> 8;
        const int n = tcnt[c * NRANGE + r];
        const int* t = tmp + TILE(c, r) * TCAP;
        for (int i = half; i < n; i += 2) atomicAdd(&cnt[t[i] >> 17], 1);
    }
    __syncthreads();
    if (tid < RNODES) {
        const int node = r * RNODES + tid;
        const int dg = cnt[tid];
        degn[node] = dg;
        const float dv = rsqrtf((float)dg + 1.0f);   // +1 = self-loop
        dvs[tid] = dv;
        if (node < N_NODES) dinv[node] = dv;
    }
    __syncthreads();
    for (int i = tid; i < RNODES * 16; i += 512) {
        const int nl = i >> 4, q = i & 15;
        const int node = r * RNODES + nl;
        if (node < N_NODES) {
            const float4 v = ((const float4*)x)[(size_t)node * 16 + q];
            const float dv = dvs[nl];
            __half2 h0 = __floats2half2_rn(v.x * dv, v.y * dv);
            __half2 h1 = __floats2half2_rn(v.z * dv, v.w * dv);
            uint2 pk;
            pk.x = *(unsigned int*)&h0;
            pk.y = *(unsigned int*)&h1;
            ((uint2*)y)[(size_t)node * 16 + q] = pk;
        }
    }
}

// K3: per-range fused CSR-in-LDS build + register-accumulated gather.
// 1024 threads: 128 groups x 8 lanes, one node per group (R6: Occ 46->54,
// 68->65.6 us; remaining limit = random L2-miss gather through LLC).
__global__ __launch_bounds__(1024) void aggb_kernel(const int* __restrict__ tmp,
                                                    const int* __restrict__ tcnt,
                                                    const int* __restrict__ degn,
                                                    const __half* __restrict__ y,
                                                    __half* __restrict__ agg) {
    __shared__ int nodelist[NLCAP];      // 18 KB
    __shared__ int sc[RNODES];           // inclusive prefix (kept: end offsets)
    __shared__ int start[RNODES];
    __shared__ int cur[RNODES];
    const int r = blockIdx.x, tid = threadIdx.x;

    int mydeg = 0;
    if (tid < RNODES) {
        mydeg = degn[r * RNODES + tid];
        sc[tid] = mydeg;
    }
    __syncthreads();
    #pragma unroll
    for (int off = 1; off < RNODES; off <<= 1) {   // Hillis-Steele inclusive
        int v = 0;
        if (tid < RNODES && tid >= off) v = sc[tid - off];
        __syncthreads();
        if (tid < RNODES) sc[tid] += v;
        __syncthreads();
    }
    if (tid < RNODES) {
        start[tid] = sc[tid] - mydeg;
        cur[tid]   = sc[tid] - mydeg;
    }
    __syncthreads();

    {   // scatter: 4 threads per tile (256 tiles, mean ~16 entries each)
        const int c = tid & 255, ph = tid >> 8;
        const int n = tcnt[c * NRANGE + r];
        const int* t = tmp + TILE(c, r) * TCAP;
        for (int i = ph; i < n; i += 4) {
            const int pk = t[i];
            const int slot = atomicAdd(&cur[pk >> 17], 1);
            if (slot < NLCAP) nodelist[slot] = pk & 0x1FFFF;
        }
    }
    __syncthreads();

    // gather: 128 groups x 8 lanes; group g handles exactly node g
    const int g = tid >> 3, lane = tid & 7;
    const uint4* y16 = (const uint4*)y;
    const int node = r * RNODES + g;
    if (node < N_NODES) {
        float accf[8];
        {
            const uint4 pk = y16[(size_t)node * 8 + lane];   // self-loop
            const __half2* h = (const __half2*)&pk;
            #pragma unroll
            for (int q = 0; q < 4; ++q) {
                const float2 f = __half22float2(h[q]);
                accf[2*q] = f.x; accf[2*q+1] = f.y;
            }
        }
        const int beg = start[g], end = sc[g];
        int j = beg;
        for (; j + 4 <= end; j += 4) {
            const int s0 = nodelist[j];
            const int s1 = nodelist[j + 1];
            const int s2 = nodelist[j + 2];
            const int s3 = nodelist[j + 3];
            const uint4 p0 = y16[(size_t)s0 * 8 + lane];
            const uint4 p1 = y16[(size_t)s1 * 8 + lane];
            const uint4 p2 = y16[(size_t)s2 * 8 + lane];
            const uint4 p3 = y16[(size_t)s3 * 8 + lane];
            const __half2* h0 = (const __half2*)&p0;
            const __half2* h1 = (const __half2*)&p1;
            const __half2* h2 = (const __half2*)&p2;
            const __half2* h3 = (const __half2*)&p3;
            #pragma unroll
            for (int q = 0; q < 4; ++q) {
                float2 f0 = __half22float2(h0[q]);
                float2 f1 = __half22float2(h1[q]);
                float2 f2 = __half22float2(h2[q]);
                float2 f3 = __half22float2(h3[q]);
                accf[2*q]   += (f0.x + f1.x) + (f2.x + f3.x);
                accf[2*q+1] += (f0.y + f1.y) + (f2.y + f3.y);
            }
        }
        for (; j < end; ++j) {
            const int s = nodelist[j];
            const uint4 pk = y16[(size_t)s * 8 + lane];
            const __half2* h = (const __half2*)&pk;
            #pragma unroll
            for (int q = 0; q < 4; ++q) {
                const float2 f = __half22float2(h[q]);
                accf[2*q] += f.x; accf[2*q+1] += f.y;
            }
        }
        uint4 o;
        __half2* oh = (__half2*)&o;
        #pragma unroll
        for (int q = 0; q < 4; ++q)
            oh[q] = __floats2half2_rn(accf[2*q], accf[2*q+1]);
        ((uint4*)agg)[(size_t)node * 8 + lane] = o;
    }
}

// K4: out[n] = relu( dinv[n]*agg[n] @ W_gcn + b_gcn ) @ W_lin + b_lin.
// 32 nodes/block, 4 nodes/thread: each 16 B W-read feeds 16 FMAs.
#define H_NPB 32
__global__ __launch_bounds__(256) void head_kernel(const __half* __restrict__ agg,
                                                   const float* __restrict__ dinv,
                                                   const float* __restrict__ W,
                                                   const float* __restrict__ b_gcn,
                                                   const float* __restrict__ W_lin,
                                                   const float* __restrict__ b_lin,
                                                   float* __restrict__ out) {
    __shared__ float4 Ws[IN_DIM * HID_DIM / 4];   // 32 KB
    __shared__ float  as[H_NPB * IN_DIM];         // 8 KB
    const int tid = threadIdx.x;

    const float4* W4 = (const float4*)W;
    #pragma unroll
    for (int i = tid; i < IN_DIM * HID_DIM / 4; i += 256) Ws[i] = W4[i];

    const int node0 = blockIdx.x * H_NPB;
    {
        const uint4 a4 = ((const uint4*)(agg + (size_t)node0 * IN_DIM))[tid];
        const __half2* h = (const __half2*)&a4;
        #pragma unroll
        for (int q = 0; q < 4; ++q) {
            const float2 f = __half22float2(h[q]);
            as[tid * 8 + 2*q]     = f.x;
            as[tid * 8 + 2*q + 1] = f.y;
        }
    }
    __syncthreads();

    const int jq = tid & 31;
    const int ng = tid >> 5;
    const float* arow = as + ng * 4 * IN_DIM;

    float4 a0 = {0,0,0,0}, a1 = {0,0,0,0}, a2 = {0,0,0,0}, a3 = {0,0,0,0};
    for (int k = 0; k < IN_DIM; ++k) {
        const float4 wv = Ws[k * 32 + jq];
        const float v0 = arow[k];
        const float v1 = arow[IN_DIM + k];
        const float v2 = arow[2 * IN_DIM + k];
        const float v3 = arow[3 * IN_DIM + k];
        a0.x += v0*wv.x; a0.y += v0*wv.y; a0.z += v0*wv.z; a0.w += v0*wv.w;
        a1.x += v1*wv.x; a1.y += v1*wv.y; a1.z += v1*wv.z; a1.w += v1*wv.w;
        a2.x += v2*wv.x; a2.y += v2*wv.y; a2.z += v2*wv.z; a2.w += v2*wv.w;
        a3.x += v3*wv.x; a3.y += v3*wv.y; a3.z += v3*wv.z; a3.w += v3*wv.w;
    }

    const float4 bg = ((const float4*)b_gcn)[jq];
    const int c0 = jq * 4;
    const float w00 = W_lin[(c0+0)*2], w01 = W_lin[(c0+0)*2+1];
    const float w10 = W_lin[(c0+1)*2], w11 = W_lin[(c0+1)*2+1];
    const float w20 = W_lin[(c0+2)*2], w21 = W_lin[(c0+2)*2+1];
    const float w30 = W_lin[(c0+3)*2], w31 = W_lin[(c0+3)*2+1];
    const float bl0 = b_lin[0], bl1 = b_lin[1];

    float4 am[4] = {a0, a1, a2, a3};
    #pragma unroll
    for (int m = 0; m < 4; ++m) {
        const int node = node0 + ng * 4 + m;
        const float dv = dinv[node];
        float4 v;
        v.x = fmaxf(am[m].x * dv + bg.x, 0.f);
        v.y = fmaxf(am[m].y * dv + bg.y, 0.f);
        v.z = fmaxf(am[m].z * dv + bg.z, 0.f);
        v.w = fmaxf(am[m].w * dv + bg.w, 0.f);
        float o0 = v.x*w00 + v.y*w10 + v.z*w20 + v.w*w30;
        float o1 = v.x*w01 + v.y*w11 + v.z*w21 + v.w*w31;
        #pragma unroll
        for (int off = 16; off > 0; off >>= 1) {
            o0 += __shfl_down(o0, off, 32);
            o1 += __shfl_down(o1, off, 32);
        }
        if (jq == 0) {
            out[(size_t)node * 2 + 0] = o0 + bl0;
            out[(size_t)node * 2 + 1] = o1 + bl1;
        }
    }
}

extern "C" void kernel_launch(void* const* d_in, const int* in_sizes, int n_in,
                              void* d_out, int out_size, void* d_ws, size_t ws_size,
                              hipStream_t stream) {
    const float* x     = (const float*)d_in[0];
    const int*   ei    = (const int*)  d_in[1];   // [2, E]: row 0 = src, row 1 = dst
    const float* W_gcn = (const float*)d_in[2];
    const float* b_gcn = (const float*)d_in[3];
    const float* W_lin = (const float*)d_in[4];
    const float* b_lin = (const float*)d_in[5];
    float* out = (float*)d_out;

    // workspace: tmp[200192*48 = 38.4 MB] | tcnt[200192] | degn[100096] |
    //            dinv[100000 f] | y[12.8 MB] | agg[12.8 MB]  ~= 65 MB total.
    // No aliasing, no memset (everything fully written before read).
    int*    tmp  = (int*)d_ws;
    int*    tcnt = tmp + (size_t)NRANGE * PCHUNK * TCAP;
    int*    degn = tcnt + NRANGE * PCHUNK;
    float*  dinv = (float*)(degn + NRANGE * RNODES);
    __half* y    = (__half*)(dinv + N_NODES);
    __half* agg  = y + (size_t)N_NODES * IN_DIM;

    const int* src = ei;
    const int* dst = ei + N_EDGES;

    part_kernel<<<PCHUNK, 1024, 0, stream>>>(src, dst, tmp, tcnt);
    degscale_kernel<<<NRANGE, 512, 0, stream>>>(tmp, tcnt, x, degn, dinv, y);
    aggb_kernel<<<NRANGE, 1024, 0, stream>>>(tmp, tcnt, degn, y, agg);
    head_kernel<<<N_NODES / H_NPB, 256, 0, stream>>>(agg, dinv, W_gcn, b_gcn, W_lin, b_lin, out);
}